// Round 1
// baseline (509.745 us; speedup 1.0000x reference)
//
#include <hip/hip_runtime.h>

typedef __attribute__((ext_vector_type(8))) short bf16x8;
typedef __attribute__((ext_vector_type(4))) float f32x4;

#define HW      112
#define CH      64
#define PIX_IMG (HW*HW)            // 12544
#define N4TOT   (64*112*112*64/4)  // 12845056 float4s in x
#define NPIX_F  802816.0f          // 64*112*112

__device__ __forceinline__ unsigned short f2bf(float f) {
  unsigned u = __float_as_uint(f);
  u += 0x7FFFu + ((u >> 16) & 1u);   // round-to-nearest-even
  return (unsigned short)(u >> 16);
}

// ---------------- kernel 0: zero the stat accumulators ----------------
__global__ void zero_ws(float* __restrict__ ws) {
  ws[threadIdx.x] = 0.0f;   // 128 threads: sum[64], sumsq[64]
}

// ---------------- kernel 1: per-channel sum / sumsq ----------------
__global__ __launch_bounds__(256) void stats_kernel(const float* __restrict__ x,
                                                    float* __restrict__ ws) {
  __shared__ float red[128];
  const int tid = threadIdx.x;
  if (tid < 128) red[tid] = 0.0f;
  __syncthreads();

  const float4* __restrict__ x4 = (const float4*)x;
  float4 s = make_float4(0.f, 0.f, 0.f, 0.f);
  float4 q = make_float4(0.f, 0.f, 0.f, 0.f);
  const int stride = gridDim.x * 256;
  #pragma unroll 4
  for (int i = blockIdx.x * 256 + tid; i < N4TOT; i += stride) {
    float4 v = x4[i];
    s.x += v.x; s.y += v.y; s.z += v.z; s.w += v.w;
    q.x = fmaf(v.x, v.x, q.x); q.y = fmaf(v.y, v.y, q.y);
    q.z = fmaf(v.z, v.z, q.z); q.w = fmaf(v.w, v.w, q.w);
  }
  // channel group is lane-static: floats 4*i+j have channel (4*i+j)&63; stride%16==0
  const int c0 = (tid & 15) * 4;
  atomicAdd(&red[c0 + 0], s.x); atomicAdd(&red[c0 + 1], s.y);
  atomicAdd(&red[c0 + 2], s.z); atomicAdd(&red[c0 + 3], s.w);
  atomicAdd(&red[64 + c0 + 0], q.x); atomicAdd(&red[64 + c0 + 1], q.y);
  atomicAdd(&red[64 + c0 + 2], q.z); atomicAdd(&red[64 + c0 + 3], q.w);
  __syncthreads();
  if (tid < 128) atomicAdd(&ws[tid], red[tid]);
}

// ---------------- kernel 2: scale/bias ----------------
__global__ void finalize_kernel(const float* __restrict__ beta, float* __restrict__ ws) {
  const int c = threadIdx.x;  // 64 threads
  float mean = ws[c] / NPIX_F;
  float var  = ws[64 + c] / NPIX_F - mean * mean;
  var = fmaxf(var, 0.0f);
  float sc = rsqrtf(var + 1e-5f);
  ws[128 + c] = sc;
  ws[192 + c] = beta[c] - mean * sc;   // x_bn = x*sc + bias
}

// ---------------- kernel 3: weights HWIO -> [tap][co][ci] bf16 ----------------
__global__ __launch_bounds__(256) void prep_w(const float* __restrict__ k,
                                              unsigned short* __restrict__ wsw) {
  const int idx = blockIdx.x * 256 + threadIdx.x;  // 36864 total
  const int tap = idx >> 12;
  const int co  = (idx >> 6) & 63;
  const int ci  = idx & 63;
  wsw[idx] = f2bf(k[(tap * 64 + ci) * 64 + co]);
}

// ---------------- kernel 4: fused BN-normalize + 3x3 conv (implicit GEMM, MFMA) ----
// Block: 448 threads (7 waves). One block = 2 output rows of one image.
// LDS X: 4 input rows x 114 px (w=-1..112, borders zeroed) x 64 ci bf16,
//        rows padded to 72 ushorts (144 B) for bank-conflict-free b128 reads.
// LDS W: per-tap [64 co][64 ci] bf16, same 144-B row pad.
// Per wave: D tile = [co 0..63] x [16 px] x 2 rows; W is the MFMA A operand
// (m=cout), X is B (n=pixel) => each lane's 4 acc floats are 4 consecutive cout
// => float4 epilogue stores.
__global__ __launch_bounds__(448, 4) void conv_kernel(const float* __restrict__ x,
                                                      const unsigned short* __restrict__ wsw,
                                                      const float* __restrict__ ws,
                                                      float* __restrict__ out) {
  __shared__ unsigned short Xs[4 * 114 * 72];  // 65,664 B
  __shared__ unsigned short Wl[64 * 72];       //  9,216 B
  const int tid = threadIdx.x;
  const int bid = blockIdx.x;
  const int n  = bid / 56;
  const int h0 = (bid % 56) * 2;

  const int f4  = tid & 15;
  const int ci0 = f4 * 4;
  const float4 s4 = *(const float4*)(ws + 128 + ci0);
  const float4 b4 = *(const float4*)(ws + 192 + ci0);

  // ---- stage X once: rows h0-1 .. h0+2, px 0..113 (w = px-1) ----
  const int pp0 = tid >> 4;  // 0..27
  for (int ir = 0; ir < 4; ++ir) {
    const int g = h0 - 1 + ir;
    const bool rowok = ((unsigned)g < 112u);
    const float* xrow = x + ((n * 112 + (rowok ? g : 0)) * 112) * 64;
    for (int pp = pp0; pp < 114; pp += 28) {
      const int w = pp - 1;
      float4 v = make_float4(0.f, 0.f, 0.f, 0.f);
      if (rowok && (unsigned)w < 112u) v = *(const float4*)(xrow + w * 64 + ci0);
      ushort4 o;
      o.x = f2bf(fmaf(v.x, s4.x, b4.x));
      o.y = f2bf(fmaf(v.y, s4.y, b4.y));
      o.z = f2bf(fmaf(v.z, s4.z, b4.z));
      o.w = f2bf(fmaf(v.w, s4.w, b4.w));
      *(ushort4*)(&Xs[(ir * 114 + pp) * 72 + ci0]) = o;
    }
  }
  __syncthreads();

  f32x4 acc[2][4];
  #pragma unroll
  for (int r = 0; r < 2; ++r)
    #pragma unroll
    for (int mt = 0; mt < 4; ++mt) acc[r][mt] = (f32x4){0.f, 0.f, 0.f, 0.f};

  const int lane = tid & 63;
  const int wv   = tid >> 6;    // 0..6 -> out w base = 16*wv
  const int qd   = lane >> 4;   // quad
  const int cc   = lane & 15;

  for (int tap = 0; tap < 9; ++tap) {
    // stage this tap's W slice (8 KB, L2-resident) into LDS with row pad
    for (int t = tid; t < 512; t += 448) {
      uint4 val = ((const uint4*)wsw)[tap * 512 + t];
      *((uint4*)(Wl + (t >> 3) * 72 + (t & 7) * 8)) = val;
    }
    __syncthreads();
    const int dh = tap / 3, dw = tap % 3;
    #pragma unroll
    for (int s = 0; s < 2; ++s) {
      // B operand: B[k=ci][n=px], lane n=cc, k=qd*8+j (contiguous in LDS row)
      const bf16x8 xb0 = *(const bf16x8*)(&Xs[((0 + dh) * 114 + wv * 16 + dw + cc) * 72 + s * 32 + qd * 8]);
      const bf16x8 xb1 = *(const bf16x8*)(&Xs[((1 + dh) * 114 + wv * 16 + dw + cc) * 72 + s * 32 + qd * 8]);
      #pragma unroll
      for (int mt = 0; mt < 4; ++mt) {
        // A operand: A[m=co][k=ci], lane m=cc (+16*mt), k=qd*8+j
        const bf16x8 wa = *(const bf16x8*)(&Wl[(mt * 16 + cc) * 72 + s * 32 + qd * 8]);
        acc[0][mt] = __builtin_amdgcn_mfma_f32_16x16x32_bf16(wa, xb0, acc[0][mt], 0, 0, 0);
        acc[1][mt] = __builtin_amdgcn_mfma_f32_16x16x32_bf16(wa, xb1, acc[1][mt], 0, 0, 0);
      }
    }
    __syncthreads();  // before overwriting Wl next tap
  }

  // epilogue: D[row=co][col=px]; lane holds col=cc, rows qd*4+0..3 (+16*mt)
  #pragma unroll
  for (int r = 0; r < 2; ++r) {
    const int pix = n * PIX_IMG + (h0 + r) * 112 + wv * 16 + cc;
    float* op = out + pix * 64 + qd * 4;
    #pragma unroll
    for (int mt = 0; mt < 4; ++mt) {
      *(f32x4*)(op + mt * 16) = acc[r][mt];
    }
  }
}

extern "C" void kernel_launch(void* const* d_in, const int* in_sizes, int n_in,
                              void* d_out, int out_size, void* d_ws, size_t ws_size,
                              hipStream_t stream) {
  const float* x    = (const float*)d_in[0];
  const float* kern = (const float*)d_in[1];
  const float* beta = (const float*)d_in[2];
  float* out = (float*)d_out;
  float* ws  = (float*)d_ws;
  // ws layout: [0..64) sum, [64..128) sumsq, [128..192) scale, [192..256) bias,
  //            byte 4096.. : bf16 W_sw[9][64][64] (73,728 B)
  unsigned short* wsw = (unsigned short*)((char*)d_ws + 4096);

  zero_ws<<<1, 128, 0, stream>>>(ws);
  stats_kernel<<<1024, 256, 0, stream>>>(x, ws);
  finalize_kernel<<<1, 64, 0, stream>>>(beta, ws);
  prep_w<<<144, 256, 0, stream>>>(kern, wsw);
  conv_kernel<<<64 * 56, 448, 0, stream>>>(x, wsw, ws, out);
}

// Round 2
// 483.769 us; speedup vs baseline: 1.0537x; 1.0537x over previous
//
#include <hip/hip_runtime.h>

typedef __attribute__((ext_vector_type(8))) short bf16x8;
typedef __attribute__((ext_vector_type(8))) unsigned short u16x8;
typedef __attribute__((ext_vector_type(4))) float f32x4;

#define HW      112
#define CH      64
#define PIX_IMG (HW*HW)            // 12544
#define N4TOT   (64*112*112*64/4)  // 12845056 float4s in x
#define NPIX_F  802816.0f          // 64*112*112

// ws layout (floats): [0..64) sum, [64..128) sumsq, [128..192) scale s,
// [192..256) bias b, [256..320) bias_out (= sum_tap,ci b*W).
// byte 1280: hv bf16[64] = bf16(-b/s)  (raw-x halo value -> x_bn == 0)
// byte 4096: W' bf16 [half][tap][qd][co][8]  (36864 ushorts, 73728 B), W' = s*W
// byte 4MB : raw bf16 x [n][h][w][ci]  (102,760,448 B) when ws_size permits
#define WS_HV_BYTE  1280
#define WS_W_BYTE   4096
#define WS_XBF_BYTE (4u<<20)

__device__ __forceinline__ unsigned short f2bf(float f) {
  unsigned u = __float_as_uint(f);
  u += 0x7FFFu + ((u >> 16) & 1u);   // round-to-nearest-even
  return (unsigned short)(u >> 16);
}

// ---------------- kernel 0: zero the stat accumulators ----------------
__global__ void zero_ws(float* __restrict__ ws) {
  ws[threadIdx.x] = 0.0f;   // 128 threads: sum[64], sumsq[64]
}

// ---------------- kernel 1: per-channel sum/sumsq (+ optional raw bf16 x) ----
template <bool WRITE_BF>
__global__ __launch_bounds__(256) void stats_kernel(const float* __restrict__ x,
                                                    float* __restrict__ ws,
                                                    unsigned short* __restrict__ xbf) {
  __shared__ float red[128];
  const int tid = threadIdx.x;
  if (tid < 128) red[tid] = 0.0f;
  __syncthreads();

  const float4* __restrict__ x4 = (const float4*)x;
  float4 s = make_float4(0.f, 0.f, 0.f, 0.f);
  float4 q = make_float4(0.f, 0.f, 0.f, 0.f);
  const int stride = gridDim.x * 256;
  #pragma unroll 4
  for (int i = blockIdx.x * 256 + tid; i < N4TOT; i += stride) {
    float4 v = x4[i];
    s.x += v.x; s.y += v.y; s.z += v.z; s.w += v.w;
    q.x = fmaf(v.x, v.x, q.x); q.y = fmaf(v.y, v.y, q.y);
    q.z = fmaf(v.z, v.z, q.z); q.w = fmaf(v.w, v.w, q.w);
    if (WRITE_BF) {
      ushort4 o;
      o.x = f2bf(v.x); o.y = f2bf(v.y); o.z = f2bf(v.z); o.w = f2bf(v.w);
      *(ushort4*)(xbf + 4 * i) = o;
    }
  }
  // lanes l, l^16, l^32 share the same channel quad -> shuffle pre-reduce
  #pragma unroll
  for (int m = 16; m <= 32; m <<= 1) {
    s.x += __shfl_xor(s.x, m); s.y += __shfl_xor(s.y, m);
    s.z += __shfl_xor(s.z, m); s.w += __shfl_xor(s.w, m);
    q.x += __shfl_xor(q.x, m); q.y += __shfl_xor(q.y, m);
    q.z += __shfl_xor(q.z, m); q.w += __shfl_xor(q.w, m);
  }
  if ((tid & 63) < 16) {
    const int c0 = (tid & 15) * 4;
    atomicAdd(&red[c0 + 0], s.x); atomicAdd(&red[c0 + 1], s.y);
    atomicAdd(&red[c0 + 2], s.z); atomicAdd(&red[c0 + 3], s.w);
    atomicAdd(&red[64 + c0 + 0], q.x); atomicAdd(&red[64 + c0 + 1], q.y);
    atomicAdd(&red[64 + c0 + 2], q.z); atomicAdd(&red[64 + c0 + 3], q.w);
  }
  __syncthreads();
  if (tid < 128) atomicAdd(&ws[tid], red[tid]);
}

// ---------------- kernel 2: scale/bias/halo + bias_out = sum b*W -------------
__global__ __launch_bounds__(256) void finalize_kernel(const float* __restrict__ beta,
                                                       const float* __restrict__ k,
                                                       float* __restrict__ ws) {
  __shared__ float sb[64];
  __shared__ float part[256];
  const int tid = threadIdx.x;
  if (tid < 64) {
    float mean = ws[tid] * (1.0f / NPIX_F);
    float var  = fmaxf(ws[64 + tid] * (1.0f / NPIX_F) - mean * mean, 0.0f);
    float sc = rsqrtf(var + 1e-5f);
    float b  = beta[tid] - mean * sc;
    ws[128 + tid] = sc;
    ws[192 + tid] = b;
    ((unsigned short*)((char*)ws + WS_HV_BYTE))[tid] = f2bf(-b / sc);
    sb[tid] = b;
  }
  __syncthreads();
  const int co = tid & 63, pt = tid >> 6;
  float a = 0.f;
  #pragma unroll 8
  for (int t = pt; t < 576; t += 4)          // t = tap*64 + ci
    a = fmaf(sb[t & 63], k[t * 64 + co], a);
  part[tid] = a;
  __syncthreads();
  if (tid < 64)
    ws[256 + tid] = part[tid] + part[64 + tid] + part[128 + tid] + part[192 + tid];
}

// ---------------- kernel 3: W' = s*W, layout [half][tap][qd][co][8] ----------
__global__ __launch_bounds__(256) void prep_w(const float* __restrict__ k,
                                              const float* __restrict__ ws,
                                              unsigned short* __restrict__ wsw) {
  const int oidx = blockIdx.x * 256 + threadIdx.x;  // 36864 total
  const int j  = oidx & 7;
  const int co = (oidx >> 3) & 63;
  const int qd = (oidx >> 9) & 3;
  const int t2 = oidx >> 11;          // 0..17
  const int tap = t2 % 9;
  const int h   = t2 / 9;
  const int ci  = h * 32 + qd * 8 + j;
  wsw[oidx] = f2bf(k[(tap * 64 + ci) * 64 + co] * ws[128 + ci]);
}

// ---------------- kernel 4: 3x3 conv, implicit GEMM, raw-bf16 staging --------
// Block: 448 threads (7 waves) = 4 output rows of one image.
// LDS Xs: 6 input rows x 114 px x one 32-ci half; px stride 40 ushorts (80 B,
//         16B-aligned, 2-way-max banks). Staged as a PURE copy (scale folded
//         into W', bias into acc init, halo px pre-set to bf16(-b/s)).
// LDS Wd: double-buffered per-dh W' slice (3 taps x 4 qd x 64 co x 8 = 12288 B).
// Per wave per tap: 4 xb + 4 wa ds_read_b128 -> 16 MFMA (reads/MFMA = 0.5).
// Barriers: 8/block (was 18). LDS total 79,296 B -> 2 blocks/CU.
template <bool USE_BF>
__global__ __launch_bounds__(448, 4) void conv_kernel(const float* __restrict__ x,
                                                      const unsigned short* __restrict__ xbf,
                                                      const unsigned short* __restrict__ wsw,
                                                      const float* __restrict__ ws,
                                                      float* __restrict__ out) {
  __shared__ unsigned short Xs[6 * 114 * 40];  // 54,720 B
  __shared__ unsigned short Wd[2 * 6144];      // 24,576 B
  const int tid = threadIdx.x;
  const int bid = blockIdx.x;
  const int n  = bid / 28;
  const int h0 = (bid % 28) * 4;

  const int lane = tid & 63;
  const int wv   = tid >> 6;    // 0..6 -> out w base = 16*wv
  const int qd   = lane >> 4;
  const int cc   = lane & 15;
  const int wvb  = wv * 16;

  const unsigned short* hv = (const unsigned short*)((const char*)ws + WS_HV_BYTE);

  // acc init = bias_out (covers the +b term for every tap; halo yields 0)
  f32x4 acc[4][4];
  {
    const float* bo = ws + 256;
    #pragma unroll
    for (int mt = 0; mt < 4; ++mt) {
      const f32x4 bv = *(const f32x4*)(bo + mt * 16 + qd * 4);
      #pragma unroll
      for (int r = 0; r < 4; ++r) acc[r][mt] = bv;
    }
  }

  for (int half = 0; half < 2; ++half) {
    // ---- stage Xs: rows h0-1..h0+4, px 0..113, ci' = half*32 .. +32 ----
    {
      u16x8 hv8[4];
      #pragma unroll
      for (int o = 0; o < 4; ++o) hv8[o] = *(const u16x8*)(hv + half * 32 + o * 8);
      for (int c = tid; c < 2736; c += 448) {
        const int o  = c & 3;
        const int pi = c >> 2;        // r*114 + p
        const int p  = pi % 114;
        const int r  = pi / 114;
        const int w  = p - 1;
        const int g  = h0 + r - 1;
        u16x8 v;
        if ((unsigned)w < 112u && (unsigned)g < 112u) {
          const int base = ((n * 112 + g) * 112 + w) * 64 + half * 32 + o * 8;
          if (USE_BF) {
            v = *(const u16x8*)(xbf + base);
          } else {
            const float* sp = x + base;
            const float4 a = *(const float4*)sp;
            const float4 b = *(const float4*)(sp + 4);
            v = (u16x8){f2bf(a.x), f2bf(a.y), f2bf(a.z), f2bf(a.w),
                        f2bf(b.x), f2bf(b.y), f2bf(b.z), f2bf(b.w)};
          }
        } else {
          v = hv8[o];
        }
        *(u16x8*)(&Xs[pi * 40 + o * 8]) = v;
      }
    }
    // ---- stage Wd[0] for dh=0 of this half ----
    const unsigned short* wh = wsw + half * 18432;
    for (int t = tid; t < 768; t += 448)
      *(u16x8*)(&Wd[t * 8]) = *(const u16x8*)(wh + t * 8);
    __syncthreads();

    for (int dh = 0; dh < 3; ++dh) {
      // prefetch next dh's W into the other buffer (unused since last barrier)
      if (dh < 2) {
        const unsigned short* ws_src = wh + (dh + 1) * 6144;
        const int nb = ((dh + 1) & 1) * 6144;
        for (int t = tid; t < 768; t += 448)
          *(u16x8*)(&Wd[nb + t * 8]) = *(const u16x8*)(ws_src + t * 8);
      }
      const int cb = (dh & 1) * 6144;
      #pragma unroll
      for (int dw = 0; dw < 3; ++dw) {
        bf16x8 xb[4];
        #pragma unroll
        for (int r = 0; r < 4; ++r)
          xb[r] = *(const bf16x8*)(&Xs[((r + dh) * 114 + wvb + dw + cc) * 40 + qd * 8]);
        #pragma unroll
        for (int mt = 0; mt < 4; ++mt) {
          const bf16x8 wa = *(const bf16x8*)(&Wd[cb + ((dw * 4 + qd) * 64 + mt * 16 + cc) * 8]);
          #pragma unroll
          for (int r = 0; r < 4; ++r)
            acc[r][mt] = __builtin_amdgcn_mfma_f32_16x16x32_bf16(wa, xb[r], acc[r][mt], 0, 0, 0);
        }
      }
      __syncthreads();   // guards Wd[dh&1] reuse and (dh==2) Xs restage
    }
  }

  // epilogue: lane holds px col = cc, co rows = mt*16 + qd*4 + 0..3
  #pragma unroll
  for (int r = 0; r < 4; ++r) {
    const int pix = n * PIX_IMG + (h0 + r) * 112 + wvb + cc;
    float* op = out + pix * 64 + qd * 4;
    #pragma unroll
    for (int mt = 0; mt < 4; ++mt)
      *(f32x4*)(op + mt * 16) = acc[r][mt];
  }
}

extern "C" void kernel_launch(void* const* d_in, const int* in_sizes, int n_in,
                              void* d_out, int out_size, void* d_ws, size_t ws_size,
                              hipStream_t stream) {
  const float* x    = (const float*)d_in[0];
  const float* kern = (const float*)d_in[1];
  const float* beta = (const float*)d_in[2];
  float* out = (float*)d_out;
  float* ws  = (float*)d_ws;
  unsigned short* wsw = (unsigned short*)((char*)d_ws + WS_W_BYTE);
  unsigned short* xbf = (unsigned short*)((char*)d_ws + WS_XBF_BYTE);

  const bool use_bf = ws_size >= (size_t)WS_XBF_BYTE + 102760448ull;

  zero_ws<<<1, 128, 0, stream>>>(ws);
  if (use_bf) stats_kernel<true ><<<1024, 256, 0, stream>>>(x, ws, xbf);
  else        stats_kernel<false><<<1024, 256, 0, stream>>>(x, ws, xbf);
  finalize_kernel<<<1, 256, 0, stream>>>(beta, kern, ws);
  prep_w<<<144, 256, 0, stream>>>(kern, ws, wsw);
  if (use_bf) conv_kernel<true ><<<64 * 28, 448, 0, stream>>>(x, xbf, wsw, ws, out);
  else        conv_kernel<false><<<64 * 28, 448, 0, stream>>>(x, xbf, wsw, ws, out);
}